// Round 8
// baseline (249.530 us; speedup 1.0000x reference)
//
#include <hip/hip_runtime.h>
#include <cstdint>
#include <cstddef>

constexpr int V   = 128001;
constexpr int D   = 128;
constexpr int S   = 200;
constexpr int E   = 409600;
constexpr int G4  = 512;
constexpr int CAP = 8192;

typedef _Float16 h2 __attribute__((ext_vector_type(2)));

__device__ __forceinline__ float rcp_fast(float x) {
    float r;
    asm volatile("v_rcp_f32 %0, %1" : "=v"(r) : "v"(x));
    return r;
}
__device__ __forceinline__ float sigmoid_fast(float x) {
    x = fminf(fmaxf(x, -15.f), 15.f);
    return rcp_fast(1.f + __expf(-x));
}
__device__ __forceinline__ float tanh_fast(float x) {
    x = fminf(fmaxf(x, -7.5f), 7.5f);
    float e = __expf(2.f * x);
    return (e - 1.f) * rcp_fast(e + 1.f);
}
__device__ __forceinline__ float fdot2(h2 a, h2 b, float c) {
#if defined(__has_builtin) && __has_builtin(__builtin_amdgcn_fdot2)
    return __builtin_amdgcn_fdot2(a, b, c, false);
#else
    float r;
    asm volatile("v_dot2_f32_f16 %0, %1, %2, %3" : "=v"(r) : "v"(a), "v"(b), "v"(c));
    return r;
#endif
}

// ---------------- degree pass + edge filter (dst % 200 == 199) ----------------
__global__ void k_deg_filter(const int* __restrict__ src, const int* __restrict__ dst,
                             int* __restrict__ deg_out, int* __restrict__ degr,
                             int* __restrict__ ecount, int2* __restrict__ elist)
{
    int e = blockIdx.x * blockDim.x + threadIdx.x;
    if (e >= E) return;
    int s = src[e], d = dst[e];
    atomicAdd(&deg_out[s], 1);
    if (d % S == S - 1) {
        int b = d / S;
        atomicAdd(&degr[b], 1);
        int p = atomicAdd(ecount, 1);
        if (p < CAP) elist[p] = make_int2(s, b);
    }
}

// ---------------- aggregate filtered edges ----------------
__global__ void k_agg(const int2* __restrict__ elist, const int* __restrict__ ecount,
                      const int* __restrict__ gnodes, const float* __restrict__ emb,
                      const int* __restrict__ deg_out, float* __restrict__ agg64)
{
    int cnt = *ecount; if (cnt > CAP) cnt = CAP;
    int idx = blockIdx.x * 2 + (threadIdx.x >> 7);
    int d   = threadIdx.x & 127;
    if (idx >= cnt) return;
    int2 eb = elist[idx];
    int s = eb.x, b = eb.y;
    int dg = deg_out[s];
    float ns = (dg > 0) ? rsqrtf((float)dg) : 0.f;
    float v = emb[(size_t)gnodes[s] * D + d] * ns;
    atomicAdd(&agg64[b * D + d], v);
}

// ---------------- h64 = relu((agg64 * n_dst) @ gW + gb), 64x128 ----------------
__global__ __launch_bounds__(512) void k_h64(const float* __restrict__ agg64,
                                             const int* __restrict__ degr,
                                             const float* __restrict__ gW,
                                             const float* __restrict__ gb,
                                             float* __restrict__ h64)
{
    __shared__ float a[64][128];
    for (int i = threadIdx.x; i < 64 * 128; i += blockDim.x) {
        int b = i >> 7;
        int dg = degr[b];
        float nd = (dg > 0) ? rsqrtf((float)dg) : 0.f;
        a[b][i & 127] = agg64[i] * nd;
    }
    __syncthreads();
    int j  = threadIdx.x & 127;
    int bg = threadIdx.x >> 7;
    float acc[16];
    float bias = gb[j];
#pragma unroll
    for (int ii = 0; ii < 16; ++ii) acc[ii] = bias;
    for (int k = 0; k < 128; ++k) {
        float w = gW[k * 128 + j];
#pragma unroll
        for (int ii = 0; ii < 16; ++ii) acc[ii] = fmaf(a[bg * 16 + ii][k], w, acc[ii]);
    }
#pragma unroll
    for (int ii = 0; ii < 16; ++ii)
        h64[(bg * 16 + ii) * 128 + j] = fmaxf(acc[ii], 0.f);
}

// ---------------- Gpre[t][u] = A[t] . Wih[u] + b1[u] + b2[u]  (64 x 512) ----------------
__global__ __launch_bounds__(256) void k_gemmG(const float* __restrict__ A,
                                               const float* __restrict__ Wih,
                                               const float* __restrict__ b1,
                                               const float* __restrict__ b2,
                                               float* __restrict__ Gpre)
{
    __shared__ float a[16][128];
    int tq = blockIdx.x >> 1;
    int ub = blockIdx.x & 1;
    for (int i = threadIdx.x; i < 16 * 128; i += 256)
        a[i >> 7][i & 127] = A[(tq * 16 + (i >> 7)) * 128 + (i & 127)];
    __syncthreads();
    int u = ub * 256 + threadIdx.x;
    float bias = b1[u] + b2[u];
    float acc[16];
#pragma unroll
    for (int t = 0; t < 16; ++t) acc[t] = bias;
    const float4* wr = reinterpret_cast<const float4*>(Wih + (size_t)u * 128);
    for (int k4 = 0; k4 < 32; ++k4) {
        float4 w4 = wr[k4];
#pragma unroll
        for (int t = 0; t < 16; ++t) {
            float4 av = *reinterpret_cast<const float4*>(&a[t][k4 * 4]);
            acc[t] += fmaf(w4.x, av.x, fmaf(w4.y, av.y, fmaf(w4.z, av.z, w4.w * av.w)));
        }
    }
#pragma unroll
    for (int t = 0; t < 16; ++t) Gpre[(tq * 16 + t) * G4 + u] = acc[t];
}

// ---------------- single-row LSTM: Whh staged fp16 in LDS (compiler-proof) ----------------
__global__ __launch_bounds__(512, 1) void k_lstm(const float* __restrict__ Whh,   // 512 x 128
                                                 const float* __restrict__ Gpre,  // 64 x 512
                                                 const float* __restrict__ h0row, // 128
                                                 const float* __restrict__ c0row, // 128
                                                 float* __restrict__ hout)        // 64 x 128
{
    __shared__ _Float16 wlds[512 * 128];   // 128 KB, swizzled 16B chunks
    __shared__ h2       hh[2][64];
    __shared__ float    actlds[512];
    const int u = threadIdx.x;

    for (int it = 0; it < 32; ++it) {
        int idx = it * 512 + u;
        int row = idx >> 5;
        int c4  = idx & 31;
        float4 t4 = reinterpret_cast<const float4*>(Whh)[idx];
        int k   = c4 >> 1;
        int off = (c4 & 1) * 4;
        _Float16* dst = &wlds[row * 128 + 8 * (k ^ (row & 15)) + off];
        h2 p0 = {(_Float16)t4.x, (_Float16)t4.y};
        h2 p1 = {(_Float16)t4.z, (_Float16)t4.w};
        *reinterpret_cast<h2*>(dst)     = p0;
        *reinterpret_cast<h2*>(dst + 2) = p1;
    }
    float c = 0.f;
    if (u < 64) {
        h2 p = {(_Float16)h0row[2 * u], (_Float16)h0row[2 * u + 1]};
        hh[0][u] = p;
    }
    if (u < 128) c = c0row[u];
    float gp = Gpre[u];
    const int gateType = u >> 7;
    const int swz = u & 15;
    __syncthreads();

    union Chunk { float4 f4; h2 h[4]; };
    for (int t = 0; t < 64; ++t) {
        float gp_next = (t + 1 < 64) ? Gpre[(t + 1) * G4 + u] : 0.f;
        const float4* hrow = reinterpret_cast<const float4*>(&hh[t & 1][0]);
        float a0 = 0.f, a1 = 0.f, a2 = 0.f, a3 = 0.f;
#pragma unroll
        for (int k = 0; k < 16; ++k) {
            Chunk wc, hc;
            wc.f4 = *reinterpret_cast<const float4*>(&wlds[u * 128 + 8 * (k ^ swz)]);
            hc.f4 = hrow[k];
            a0 = fdot2(wc.h[0], hc.h[0], a0);
            a1 = fdot2(wc.h[1], hc.h[1], a1);
            a2 = fdot2(wc.h[2], hc.h[2], a2);
            a3 = fdot2(wc.h[3], hc.h[3], a3);
        }
        float g = gp + ((a0 + a1) + (a2 + a3));
        gp = gp_next;
        actlds[u] = (gateType == 2) ? tanh_fast(g) : sigmoid_fast(g);
        __syncthreads();
        if (u < 128) {
            float ai = actlds[u], af = actlds[u + 128], ag = actlds[u + 256], ao = actlds[u + 384];
            c = af * c + ai * ag;
            float hn = ao * tanh_fast(c);
            reinterpret_cast<_Float16*>(&hh[(t + 1) & 1][0])[u] = (_Float16)hn;
            hout[t * 128 + u] = hn;
        }
        __syncthreads();
    }
}

// ---------------- logits: 64 x 128001, 4 v-rows x 16 b-cols per thread ----------------
// DS-pipe fix: 16 ds_read_b128 per k4 (was 32) -> DS 192 cyc/wave << VALU 512.
// Single-dim grid: all b-quarters sharing a fcW row live in the SAME block (L1
// reuse), so no cross-block duplication of the fcW stream (R2 lesson).
__global__ __launch_bounds__(512, 1) void k_fc(const float* __restrict__ out64,
                                               const float* __restrict__ fcW,
                                               const float* __restrict__ fcb,
                                               float* __restrict__ logits)
{
    __shared__ float ol[64][128];
    const int tid = threadIdx.x;
    for (int i = tid; i < 64 * 128; i += 512) ol[i >> 7][i & 127] = out64[i];
    __syncthreads();
    const int l  = tid & 127;              // v-lane
    const int q  = tid >> 7;               // b-quarter
    const int b0 = q * 16;
    int v[4];
    const float4* W[4];
    float acc[4][16];
#pragma unroll
    for (int r = 0; r < 4; ++r) {
        v[r] = blockIdx.x * 512 + r * 128 + l;
        int vc = v[r] < V ? v[r] : V - 1;
        W[r] = reinterpret_cast<const float4*>(fcW + (size_t)vc * 128);
        float fb = fcb[vc];
#pragma unroll
        for (int bb = 0; bb < 16; ++bb) acc[r][bb] = fb;
    }
    for (int k4 = 0; k4 < 32; ++k4) {
        float4 w0 = W[0][k4], w1 = W[1][k4], w2 = W[2][k4], w3 = W[3][k4];
#pragma unroll
        for (int bb = 0; bb < 16; ++bb) {
            float4 a = *reinterpret_cast<const float4*>(&ol[b0 + bb][k4 * 4]);  // uniform broadcast
            acc[0][bb] += w0.x * a.x + w0.y * a.y + w0.z * a.z + w0.w * a.w;
            acc[1][bb] += w1.x * a.x + w1.y * a.y + w1.z * a.z + w1.w * a.w;
            acc[2][bb] += w2.x * a.x + w2.y * a.y + w2.z * a.z + w2.w * a.w;
            acc[3][bb] += w3.x * a.x + w3.y * a.y + w3.z * a.z + w3.w * a.w;
        }
    }
#pragma unroll
    for (int r = 0; r < 4; ++r) {
        if (v[r] < V) {
#pragma unroll
            for (int bb = 0; bb < 16; ++bb)
                logits[(size_t)(b0 + bb) * V + v[r]] = acc[r][bb];
        }
    }
}

extern "C" void kernel_launch(void* const* d_in, const int* in_sizes, int n_in,
                              void* d_out, int out_size, void* d_ws, size_t ws_size,
                              hipStream_t stream)
{
    const int*   gnodes = (const int*)d_in[0];
    const int*   src    = (const int*)d_in[1];
    const int*   dst    = (const int*)d_in[2];
    const float* emb    = (const float*)d_in[3];
    const float* gW     = (const float*)d_in[4];
    const float* gb     = (const float*)d_in[5];
    const float* Wih0   = (const float*)d_in[6];
    const float* Whh0   = (const float*)d_in[7];
    const float* bih0   = (const float*)d_in[8];
    const float* bhh0   = (const float*)d_in[9];
    const float* Wih1   = (const float*)d_in[10];
    const float* Whh1   = (const float*)d_in[11];
    const float* bih1   = (const float*)d_in[12];
    const float* bhh1   = (const float*)d_in[13];
    const float* fcW    = (const float*)d_in[14];
    const float* fcb    = (const float*)d_in[15];
    const float* h0     = (const float*)d_in[16];  // (2, 200, 128)
    const float* c0     = (const float*)d_in[17];

    char* ws = (char*)d_ws;
    int*   deg_out = (int*)(ws + 0);          // 12800 ints
    int*   degr    = (int*)(ws + 51200);      // 64 ints
    int*   ecount  = (int*)(ws + 51456);      // 1 int (+pad)
    float* agg64   = (float*)(ws + 51712);    // 64*128  -> zero region ends at 84480
    int2*  elist   = (int2*)(ws + 84480);     // CAP entries (64 KB)
    float* h64     = (float*)(ws + 150016);   // 64*128
    float* Gpre    = (float*)(ws + 182784);   // 64*512
    float* h1out   = (float*)(ws + 313856);   // 64*128
    float* out64   = (float*)(ws + 346624);   // 64*128
    float* logits  = (float*)d_out;

    hipMemsetAsync(ws, 0, 84480, stream);     // deg_out, degr, ecount, agg64

    k_deg_filter<<<E / 256, 256, 0, stream>>>(src, dst, deg_out, degr, ecount, elist);
    k_agg<<<CAP / 2, 256, 0, stream>>>(elist, ecount, gnodes, emb, deg_out, agg64);
    k_h64<<<1, 512, 0, stream>>>(agg64, degr, gW, gb, h64);

    k_gemmG<<<8, 256, 0, stream>>>(h64, Wih0, bih0, bhh0, Gpre);
    k_lstm<<<1, 512, 0, stream>>>(Whh0, Gpre, h0 + 199 * 128, c0 + 199 * 128, h1out);
    k_gemmG<<<8, 256, 0, stream>>>(h1out, Wih1, bih1, bhh1, Gpre);
    k_lstm<<<1, 512, 0, stream>>>(Whh1, Gpre, h0 + (200 + 199) * 128, c0 + (200 + 199) * 128, out64);

    k_fc<<<251, 512, 0, stream>>>(out64, fcW, fcb, logits);
}

// Round 9
// 229.183 us; speedup vs baseline: 1.0888x; 1.0888x over previous
//
#include <hip/hip_runtime.h>
#include <cstdint>
#include <cstddef>

constexpr int V   = 128001;
constexpr int D   = 128;
constexpr int S   = 200;
constexpr int E   = 409600;
constexpr int G4  = 512;
constexpr int CAP = 8192;

typedef _Float16 h2 __attribute__((ext_vector_type(2)));

__device__ __forceinline__ float rcp_fast(float x) {
    float r;
    asm volatile("v_rcp_f32 %0, %1" : "=v"(r) : "v"(x));
    return r;
}
__device__ __forceinline__ float sigmoid_fast(float x) {
    x = fminf(fmaxf(x, -15.f), 15.f);
    return rcp_fast(1.f + __expf(-x));
}
__device__ __forceinline__ float tanh_fast(float x) {
    x = fminf(fmaxf(x, -7.5f), 7.5f);
    float e = __expf(2.f * x);
    return (e - 1.f) * rcp_fast(e + 1.f);
}
__device__ __forceinline__ float fdot2(h2 a, h2 b, float c) {
#if defined(__has_builtin) && __has_builtin(__builtin_amdgcn_fdot2)
    return __builtin_amdgcn_fdot2(a, b, c, false);
#else
    float r;
    asm volatile("v_dot2_f32_f16 %0, %1, %2, %3" : "=v"(r) : "v"(a), "v"(b), "v"(c));
    return r;
#endif
}

// ---------------- degree pass + edge filter (dst % 200 == 199) ----------------
__global__ void k_deg_filter(const int* __restrict__ src, const int* __restrict__ dst,
                             int* __restrict__ deg_out, int* __restrict__ degr,
                             int* __restrict__ ecount, int2* __restrict__ elist)
{
    int e = blockIdx.x * blockDim.x + threadIdx.x;
    if (e >= E) return;
    int s = src[e], d = dst[e];
    atomicAdd(&deg_out[s], 1);
    if (d % S == S - 1) {
        int b = d / S;
        atomicAdd(&degr[b], 1);
        int p = atomicAdd(ecount, 1);
        if (p < CAP) elist[p] = make_int2(s, b);
    }
}

// ---------------- aggregate filtered edges ----------------
__global__ void k_agg(const int2* __restrict__ elist, const int* __restrict__ ecount,
                      const int* __restrict__ gnodes, const float* __restrict__ emb,
                      const int* __restrict__ deg_out, float* __restrict__ agg64)
{
    int cnt = *ecount; if (cnt > CAP) cnt = CAP;
    int idx = blockIdx.x * 2 + (threadIdx.x >> 7);
    int d   = threadIdx.x & 127;
    if (idx >= cnt) return;
    int2 eb = elist[idx];
    int s = eb.x, b = eb.y;
    int dg = deg_out[s];
    float ns = (dg > 0) ? rsqrtf((float)dg) : 0.f;
    float v = emb[(size_t)gnodes[s] * D + d] * ns;
    atomicAdd(&agg64[b * D + d], v);
}

// ---------------- h64 = relu((agg64 * n_dst) @ gW + gb), 64x128 ----------------
__global__ __launch_bounds__(512) void k_h64(const float* __restrict__ agg64,
                                             const int* __restrict__ degr,
                                             const float* __restrict__ gW,
                                             const float* __restrict__ gb,
                                             float* __restrict__ h64)
{
    __shared__ float a[64][128];
    for (int i = threadIdx.x; i < 64 * 128; i += blockDim.x) {
        int b = i >> 7;
        int dg = degr[b];
        float nd = (dg > 0) ? rsqrtf((float)dg) : 0.f;
        a[b][i & 127] = agg64[i] * nd;
    }
    __syncthreads();
    int j  = threadIdx.x & 127;
    int bg = threadIdx.x >> 7;
    float acc[16];
    float bias = gb[j];
#pragma unroll
    for (int ii = 0; ii < 16; ++ii) acc[ii] = bias;
    for (int k = 0; k < 128; ++k) {
        float w = gW[k * 128 + j];
#pragma unroll
        for (int ii = 0; ii < 16; ++ii) acc[ii] = fmaf(a[bg * 16 + ii][k], w, acc[ii]);
    }
#pragma unroll
    for (int ii = 0; ii < 16; ++ii)
        h64[(bg * 16 + ii) * 128 + j] = fmaxf(acc[ii], 0.f);
}

// ---------------- Gpre[t][u] = A[t] . Wih[u] + b1[u] + b2[u]  (64 x 512) ----------------
__global__ __launch_bounds__(256) void k_gemmG(const float* __restrict__ A,
                                               const float* __restrict__ Wih,
                                               const float* __restrict__ b1,
                                               const float* __restrict__ b2,
                                               float* __restrict__ Gpre)
{
    __shared__ float a[16][128];
    int tq = blockIdx.x >> 1;
    int ub = blockIdx.x & 1;
    for (int i = threadIdx.x; i < 16 * 128; i += 256)
        a[i >> 7][i & 127] = A[(tq * 16 + (i >> 7)) * 128 + (i & 127)];
    __syncthreads();
    int u = ub * 256 + threadIdx.x;
    float bias = b1[u] + b2[u];
    float acc[16];
#pragma unroll
    for (int t = 0; t < 16; ++t) acc[t] = bias;
    const float4* wr = reinterpret_cast<const float4*>(Wih + (size_t)u * 128);
    for (int k4 = 0; k4 < 32; ++k4) {
        float4 w4 = wr[k4];
#pragma unroll
        for (int t = 0; t < 16; ++t) {
            float4 av = *reinterpret_cast<const float4*>(&a[t][k4 * 4]);
            acc[t] += fmaf(w4.x, av.x, fmaf(w4.y, av.y, fmaf(w4.z, av.z, w4.w * av.w)));
        }
    }
#pragma unroll
    for (int t = 0; t < 16; ++t) Gpre[(tq * 16 + t) * G4 + u] = acc[t];
}

// ---------------- single-row LSTM: Whh staged fp16 in LDS (compiler-proof) ----------------
__global__ __launch_bounds__(512, 1) void k_lstm(const float* __restrict__ Whh,   // 512 x 128
                                                 const float* __restrict__ Gpre,  // 64 x 512
                                                 const float* __restrict__ h0row, // 128
                                                 const float* __restrict__ c0row, // 128
                                                 float* __restrict__ hout)        // 64 x 128
{
    __shared__ _Float16 wlds[512 * 128];   // 128 KB, swizzled 16B chunks
    __shared__ h2       hh[2][64];
    __shared__ float    actlds[512];
    const int u = threadIdx.x;

    for (int it = 0; it < 32; ++it) {
        int idx = it * 512 + u;
        int row = idx >> 5;
        int c4  = idx & 31;
        float4 t4 = reinterpret_cast<const float4*>(Whh)[idx];
        int k   = c4 >> 1;
        int off = (c4 & 1) * 4;
        _Float16* dst = &wlds[row * 128 + 8 * (k ^ (row & 15)) + off];
        h2 p0 = {(_Float16)t4.x, (_Float16)t4.y};
        h2 p1 = {(_Float16)t4.z, (_Float16)t4.w};
        *reinterpret_cast<h2*>(dst)     = p0;
        *reinterpret_cast<h2*>(dst + 2) = p1;
    }
    float c = 0.f;
    if (u < 64) {
        h2 p = {(_Float16)h0row[2 * u], (_Float16)h0row[2 * u + 1]};
        hh[0][u] = p;
    }
    if (u < 128) c = c0row[u];
    float gp = Gpre[u];
    const int gateType = u >> 7;
    const int swz = u & 15;
    __syncthreads();

    union Chunk { float4 f4; h2 h[4]; };
    for (int t = 0; t < 64; ++t) {
        float gp_next = (t + 1 < 64) ? Gpre[(t + 1) * G4 + u] : 0.f;
        const float4* hrow = reinterpret_cast<const float4*>(&hh[t & 1][0]);
        float a0 = 0.f, a1 = 0.f, a2 = 0.f, a3 = 0.f;
#pragma unroll
        for (int k = 0; k < 16; ++k) {
            Chunk wc, hc;
            wc.f4 = *reinterpret_cast<const float4*>(&wlds[u * 128 + 8 * (k ^ swz)]);
            hc.f4 = hrow[k];
            a0 = fdot2(wc.h[0], hc.h[0], a0);
            a1 = fdot2(wc.h[1], hc.h[1], a1);
            a2 = fdot2(wc.h[2], hc.h[2], a2);
            a3 = fdot2(wc.h[3], hc.h[3], a3);
        }
        float g = gp + ((a0 + a1) + (a2 + a3));
        gp = gp_next;
        actlds[u] = (gateType == 2) ? tanh_fast(g) : sigmoid_fast(g);
        __syncthreads();
        if (u < 128) {
            float ai = actlds[u], af = actlds[u + 128], ag = actlds[u + 256], ao = actlds[u + 384];
            c = af * c + ai * ag;
            float hn = ao * tanh_fast(c);
            reinterpret_cast<_Float16*>(&hh[(t + 1) & 1][0])[u] = (_Float16)hn;
            hout[t * 128 + u] = hn;
        }
        __syncthreads();
    }
}

// ---------------- logits: 64 x 128001 ----------------
// Latency-hiding shape (R8 post-mortem): 256-thr blocks, thread = (v-lane 128)
// x (b-half 2), acc[32] (~55 VGPR), ONE W-stream/thread with next-k4 prefetch.
// 32 KB LDS -> up to 5 blocks/CU; 1001 blocks -> ~16 waves/CU for latency hiding.
__global__ __launch_bounds__(256, 2) void k_fc(const float* __restrict__ out64,
                                               const float* __restrict__ fcW,
                                               const float* __restrict__ fcb,
                                               float* __restrict__ logits)
{
    __shared__ float ol[64][128];
    const int tid = threadIdx.x;
    for (int i = tid; i < 2048; i += 256)
        reinterpret_cast<float4*>(&ol[0][0])[i] = reinterpret_cast<const float4*>(out64)[i];
    __syncthreads();
    const int l  = tid & 127;              // v-lane
    const int bh = tid >> 7;               // b-half
    const int b0 = bh * 32;
    const int v  = blockIdx.x * 128 + l;
    const int vc = v < V ? v : V - 1;
    const float4* W = reinterpret_cast<const float4*>(fcW + (size_t)vc * 128);
    const float fb = fcb[vc];
    float acc[32];
#pragma unroll
    for (int bb = 0; bb < 32; ++bb) acc[bb] = fb;
    float4 w = W[0];
    for (int k4 = 0; k4 < 32; ++k4) {
        float4 wn = (k4 + 1 < 32) ? W[k4 + 1] : w;   // prefetch next 16B of the stream
#pragma unroll
        for (int bb = 0; bb < 32; ++bb) {
            float4 a = *reinterpret_cast<const float4*>(&ol[b0 + bb][k4 * 4]);  // uniform broadcast
            acc[bb] += w.x * a.x + w.y * a.y + w.z * a.z + w.w * a.w;
        }
        w = wn;
    }
    if (v < V) {
#pragma unroll
        for (int bb = 0; bb < 32; ++bb)
            logits[(size_t)(b0 + bb) * V + v] = acc[bb];
    }
}

extern "C" void kernel_launch(void* const* d_in, const int* in_sizes, int n_in,
                              void* d_out, int out_size, void* d_ws, size_t ws_size,
                              hipStream_t stream)
{
    const int*   gnodes = (const int*)d_in[0];
    const int*   src    = (const int*)d_in[1];
    const int*   dst    = (const int*)d_in[2];
    const float* emb    = (const float*)d_in[3];
    const float* gW     = (const float*)d_in[4];
    const float* gb     = (const float*)d_in[5];
    const float* Wih0   = (const float*)d_in[6];
    const float* Whh0   = (const float*)d_in[7];
    const float* bih0   = (const float*)d_in[8];
    const float* bhh0   = (const float*)d_in[9];
    const float* Wih1   = (const float*)d_in[10];
    const float* Whh1   = (const float*)d_in[11];
    const float* bih1   = (const float*)d_in[12];
    const float* bhh1   = (const float*)d_in[13];
    const float* fcW    = (const float*)d_in[14];
    const float* fcb    = (const float*)d_in[15];
    const float* h0     = (const float*)d_in[16];  // (2, 200, 128)
    const float* c0     = (const float*)d_in[17];

    char* ws = (char*)d_ws;
    int*   deg_out = (int*)(ws + 0);          // 12800 ints
    int*   degr    = (int*)(ws + 51200);      // 64 ints
    int*   ecount  = (int*)(ws + 51456);      // 1 int (+pad)
    float* agg64   = (float*)(ws + 51712);    // 64*128  -> zero region ends at 84480
    int2*  elist   = (int2*)(ws + 84480);     // CAP entries (64 KB)
    float* h64     = (float*)(ws + 150016);   // 64*128
    float* Gpre    = (float*)(ws + 182784);   // 64*512
    float* h1out   = (float*)(ws + 313856);   // 64*128
    float* out64   = (float*)(ws + 346624);   // 64*128
    float* logits  = (float*)d_out;

    hipMemsetAsync(ws, 0, 84480, stream);     // deg_out, degr, ecount, agg64

    k_deg_filter<<<E / 256, 256, 0, stream>>>(src, dst, deg_out, degr, ecount, elist);
    k_agg<<<CAP / 2, 256, 0, stream>>>(elist, ecount, gnodes, emb, deg_out, agg64);
    k_h64<<<1, 512, 0, stream>>>(agg64, degr, gW, gb, h64);

    k_gemmG<<<8, 256, 0, stream>>>(h64, Wih0, bih0, bhh0, Gpre);
    k_lstm<<<1, 512, 0, stream>>>(Whh0, Gpre, h0 + 199 * 128, c0 + 199 * 128, h1out);
    k_gemmG<<<8, 256, 0, stream>>>(h1out, Wih1, bih1, bhh1, Gpre);
    k_lstm<<<1, 512, 0, stream>>>(Whh1, Gpre, h0 + (200 + 199) * 128, c0 + (200 + 199) * 128, out64);

    k_fc<<<(V + 127) / 128, 256, 0, stream>>>(out64, fcW, fcb, logits);
}

// Round 10
// 222.624 us; speedup vs baseline: 1.1209x; 1.0295x over previous
//
#include <hip/hip_runtime.h>
#include <cstdint>
#include <cstddef>

constexpr int V   = 128001;
constexpr int D   = 128;
constexpr int S   = 200;
constexpr int E   = 409600;
constexpr int G4  = 512;
constexpr int CAP = 8192;

typedef _Float16 h2 __attribute__((ext_vector_type(2)));

__device__ __forceinline__ float rcp_fast(float x) {
    float r;
    asm volatile("v_rcp_f32 %0, %1" : "=v"(r) : "v"(x));
    return r;
}
__device__ __forceinline__ float sigmoid_fast(float x) {
    x = fminf(fmaxf(x, -15.f), 15.f);
    return rcp_fast(1.f + __expf(-x));
}
__device__ __forceinline__ float tanh_fast(float x) {
    x = fminf(fmaxf(x, -7.5f), 7.5f);
    float e = __expf(2.f * x);
    return (e - 1.f) * rcp_fast(e + 1.f);
}
__device__ __forceinline__ float fdot2(h2 a, h2 b, float c) {
#if defined(__has_builtin) && __has_builtin(__builtin_amdgcn_fdot2)
    return __builtin_amdgcn_fdot2(a, b, c, false);
#else
    float r;
    asm volatile("v_dot2_f32_f16 %0, %1, %2, %3" : "=v"(r) : "v"(a), "v"(b), "v"(c));
    return r;
#endif
}

// ---------------- degree pass + edge filter (dst % 200 == 199) ----------------
__global__ void k_deg_filter(const int* __restrict__ src, const int* __restrict__ dst,
                             int* __restrict__ deg_out, int* __restrict__ degr,
                             int* __restrict__ ecount, int2* __restrict__ elist)
{
    int e = blockIdx.x * blockDim.x + threadIdx.x;
    if (e >= E) return;
    int s = src[e], d = dst[e];
    atomicAdd(&deg_out[s], 1);
    if (d % S == S - 1) {
        int b = d / S;
        atomicAdd(&degr[b], 1);
        int p = atomicAdd(ecount, 1);
        if (p < CAP) elist[p] = make_int2(s, b);
    }
}

// ---------------- aggregate filtered edges ----------------
__global__ void k_agg(const int2* __restrict__ elist, const int* __restrict__ ecount,
                      const int* __restrict__ gnodes, const float* __restrict__ emb,
                      const int* __restrict__ deg_out, float* __restrict__ agg64)
{
    int cnt = *ecount; if (cnt > CAP) cnt = CAP;
    int idx = blockIdx.x * 2 + (threadIdx.x >> 7);
    int d   = threadIdx.x & 127;
    if (idx >= cnt) return;
    int2 eb = elist[idx];
    int s = eb.x, b = eb.y;
    int dg = deg_out[s];
    float ns = (dg > 0) ? rsqrtf((float)dg) : 0.f;
    float v = emb[(size_t)gnodes[s] * D + d] * ns;
    atomicAdd(&agg64[b * D + d], v);
}

// ---------------- h64 = relu((agg64 * n_dst) @ gW + gb), 64x128 ----------------
__global__ __launch_bounds__(512) void k_h64(const float* __restrict__ agg64,
                                             const int* __restrict__ degr,
                                             const float* __restrict__ gW,
                                             const float* __restrict__ gb,
                                             float* __restrict__ h64)
{
    __shared__ float a[64][128];
    for (int i = threadIdx.x; i < 64 * 128; i += blockDim.x) {
        int b = i >> 7;
        int dg = degr[b];
        float nd = (dg > 0) ? rsqrtf((float)dg) : 0.f;
        a[b][i & 127] = agg64[i] * nd;
    }
    __syncthreads();
    int j  = threadIdx.x & 127;
    int bg = threadIdx.x >> 7;
    float acc[16];
    float bias = gb[j];
#pragma unroll
    for (int ii = 0; ii < 16; ++ii) acc[ii] = bias;
    for (int k = 0; k < 128; ++k) {
        float w = gW[k * 128 + j];
#pragma unroll
        for (int ii = 0; ii < 16; ++ii) acc[ii] = fmaf(a[bg * 16 + ii][k], w, acc[ii]);
    }
#pragma unroll
    for (int ii = 0; ii < 16; ++ii)
        h64[(bg * 16 + ii) * 128 + j] = fmaxf(acc[ii], 0.f);
}

// ---------------- Gpre0[t][u] = A[t] . Wih0[u] + b1[u] + b2[u]  (64 x 512) ----------------
__global__ __launch_bounds__(256) void k_gemmG(const float* __restrict__ A,
                                               const float* __restrict__ Wih,
                                               const float* __restrict__ b1,
                                               const float* __restrict__ b2,
                                               float* __restrict__ Gpre)
{
    __shared__ float a[16][128];
    int tq = blockIdx.x >> 1;
    int ub = blockIdx.x & 1;
    for (int i = threadIdx.x; i < 16 * 128; i += 256)
        a[i >> 7][i & 127] = A[(tq * 16 + (i >> 7)) * 128 + (i & 127)];
    __syncthreads();
    int u = ub * 256 + threadIdx.x;
    float bias = b1[u] + b2[u];
    float acc[16];
#pragma unroll
    for (int t = 0; t < 16; ++t) acc[t] = bias;
    const float4* wr = reinterpret_cast<const float4*>(Wih + (size_t)u * 128);
    for (int k4 = 0; k4 < 32; ++k4) {
        float4 w4 = wr[k4];
#pragma unroll
        for (int t = 0; t < 16; ++t) {
            float4 av = *reinterpret_cast<const float4*>(&a[t][k4 * 4]);
            acc[t] += fmaf(w4.x, av.x, fmaf(w4.y, av.y, fmaf(w4.z, av.z, w4.w * av.w)));
        }
    }
#pragma unroll
    for (int t = 0; t < 16; ++t) Gpre[(tq * 16 + t) * G4 + u] = acc[t];
}

// ---------------- pipelined 2-layer LSTM: 3 co-resident blocks ----------------
// role 0: layer-0 recurrence (Whh0 fp16 in LDS, Gpre0 from global) -> h0glob[t], flagA
// role 1: Gpre1[t] = Wih1 . h0glob[t] + bias (Wih1 fp16 in LDS)    -> gpre1[t], flagB
// role 2: layer-1 recurrence (Whh1 fp16 in LDS)                    -> out64[t]
// Handoff: monotonic flags, agent-scope release/acquire (cross-XCD safe).
__global__ __launch_bounds__(512, 1) void k_lstm_pipe(
    const float* __restrict__ Whh0, const float* __restrict__ Wih1,
    const float* __restrict__ Whh1, const float* __restrict__ Gpre0,
    const float* __restrict__ bih1, const float* __restrict__ bhh1,
    const float* __restrict__ h00, const float* __restrict__ c00,
    const float* __restrict__ h01, const float* __restrict__ c01,
    float* __restrict__ h0glob, float* __restrict__ gpre1,
    float* __restrict__ out64, int* __restrict__ flagA, int* __restrict__ flagB)
{
    __shared__ _Float16 wlds[512 * 128];   // 128 KB, swizzled 16B chunks
    __shared__ h2       hh[2][64];
    __shared__ float    actlds[512];
    const int u    = threadIdx.x;
    const int role = blockIdx.x;
    const float* M = (role == 0) ? Whh0 : (role == 1) ? Wih1 : Whh1;

    for (int it = 0; it < 32; ++it) {
        int idx = it * 512 + u;
        int row = idx >> 5;
        int c4  = idx & 31;
        float4 t4 = reinterpret_cast<const float4*>(M)[idx];
        int k   = c4 >> 1;
        int off = (c4 & 1) * 4;
        _Float16* dst = &wlds[row * 128 + 8 * (k ^ (row & 15)) + off];
        h2 p0 = {(_Float16)t4.x, (_Float16)t4.y};
        h2 p1 = {(_Float16)t4.z, (_Float16)t4.w};
        *reinterpret_cast<h2*>(dst)     = p0;
        *reinterpret_cast<h2*>(dst + 2) = p1;
    }
    const int swz = u & 15;
    union Chunk { float4 f4; h2 h[4]; };

#define DOT_BODY(G_OUT)                                                          \
    {                                                                            \
        float a0 = 0.f, a1 = 0.f, a2 = 0.f, a3 = 0.f;                            \
        _Pragma("unroll")                                                        \
        for (int k = 0; k < 16; ++k) {                                           \
            Chunk wc, hc;                                                        \
            wc.f4 = *reinterpret_cast<const float4*>(&wlds[u * 128 + 8 * (k ^ swz)]); \
            hc.f4 = hrow[k];                                                     \
            a0 = fdot2(wc.h[0], hc.h[0], a0);                                    \
            a1 = fdot2(wc.h[1], hc.h[1], a1);                                    \
            a2 = fdot2(wc.h[2], hc.h[2], a2);                                    \
            a3 = fdot2(wc.h[3], hc.h[3], a3);                                    \
        }                                                                        \
        G_OUT = ((a0 + a1) + (a2 + a3));                                         \
    }

    if (role == 0) {
        float c = 0.f;
        if (u < 64) { h2 p = {(_Float16)h00[2 * u], (_Float16)h00[2 * u + 1]}; hh[0][u] = p; }
        if (u < 128) c = c00[u];
        float gp = Gpre0[u];
        __syncthreads();
        for (int t = 0; t < 64; ++t) {
            float gp_next = (t + 1 < 64) ? Gpre0[(t + 1) * G4 + u] : 0.f;
            const float4* hrow = reinterpret_cast<const float4*>(&hh[t & 1][0]);
            float d; DOT_BODY(d);
            float g = gp + d;
            gp = gp_next;
            actlds[u] = ((u >> 7) == 2) ? tanh_fast(g) : sigmoid_fast(g);
            __syncthreads();
            if (u < 128) {
                float ai = actlds[u], af = actlds[u + 128], ag = actlds[u + 256], ao = actlds[u + 384];
                c = af * c + ai * ag;
                float hn = ao * tanh_fast(c);
                reinterpret_cast<_Float16*>(&hh[(t + 1) & 1][0])[u] = (_Float16)hn;
                h0glob[t * 128 + u] = hn;
            }
            __syncthreads();   // drains the h0glob stores (vmcnt(0) before barrier)
            if (u == 0) __hip_atomic_store(flagA, t + 1, __ATOMIC_RELEASE, __HIP_MEMORY_SCOPE_AGENT);
        }
    } else if (role == 1) {
        float bias = bih1[u] + bhh1[u];
        __syncthreads();
        for (int t = 0; t < 64; ++t) {
            if (u == 0) {
                int spins = 0;
                while (__hip_atomic_load(flagA, __ATOMIC_ACQUIRE, __HIP_MEMORY_SCOPE_AGENT) < t + 1) {
                    __builtin_amdgcn_s_sleep(2);
                    if (++spins > 10000000) break;   // fail loud (wrong data), never hang
                }
            }
            __syncthreads();
            if (u < 64) {
                h2 p = {(_Float16)h0glob[t * 128 + 2 * u], (_Float16)h0glob[t * 128 + 2 * u + 1]};
                hh[0][u] = p;
            }
            __syncthreads();
            const float4* hrow = reinterpret_cast<const float4*>(&hh[0][0]);
            float d; DOT_BODY(d);
            gpre1[t * 512 + u] = bias + d;
            __syncthreads();   // drain stores before publishing
            if (u == 0) __hip_atomic_store(flagB, t + 1, __ATOMIC_RELEASE, __HIP_MEMORY_SCOPE_AGENT);
        }
    } else {
        float c = 0.f;
        if (u < 64) { h2 p = {(_Float16)h01[2 * u], (_Float16)h01[2 * u + 1]}; hh[0][u] = p; }
        if (u < 128) c = c01[u];
        __syncthreads();
        for (int t = 0; t < 64; ++t) {
            if (u == 0) {
                int spins = 0;
                while (__hip_atomic_load(flagB, __ATOMIC_ACQUIRE, __HIP_MEMORY_SCOPE_AGENT) < t + 1) {
                    __builtin_amdgcn_s_sleep(2);
                    if (++spins > 10000000) break;
                }
            }
            __syncthreads();
            float gp = gpre1[t * 512 + u];        // issued here, latency hides under dot
            const float4* hrow = reinterpret_cast<const float4*>(&hh[t & 1][0]);
            float d; DOT_BODY(d);
            float g = gp + d;
            actlds[u] = ((u >> 7) == 2) ? tanh_fast(g) : sigmoid_fast(g);
            __syncthreads();
            if (u < 128) {
                float ai = actlds[u], af = actlds[u + 128], ag = actlds[u + 256], ao = actlds[u + 384];
                c = af * c + ai * ag;
                float hn = ao * tanh_fast(c);
                reinterpret_cast<_Float16*>(&hh[(t + 1) & 1][0])[u] = (_Float16)hn;
                out64[t * 128 + u] = hn;
            }
            __syncthreads();
        }
    }
#undef DOT_BODY
}

// ---------------- logits: 64 x 128001 ----------------
// 64 v-lanes x 4 b-quarters, acc[16] (~40 VGPR), depth-2 W prefetch, grid 2001.
// 32 KB LDS -> 5 blocks/CU -> ~5 waves/SIMD for W-stream latency hiding.
__global__ __launch_bounds__(256, 4) void k_fc(const float* __restrict__ out64,
                                               const float* __restrict__ fcW,
                                               const float* __restrict__ fcb,
                                               float* __restrict__ logits)
{
    __shared__ float ol[64][128];
    const int tid = threadIdx.x;
    for (int i = tid; i < 2048; i += 256)
        reinterpret_cast<float4*>(&ol[0][0])[i] = reinterpret_cast<const float4*>(out64)[i];
    __syncthreads();
    const int l  = tid & 63;               // v-lane
    const int q  = tid >> 6;               // b-quarter
    const int b0 = q * 16;
    const int v  = blockIdx.x * 64 + l;
    const int vc = v < V ? v : V - 1;
    const float4* W = reinterpret_cast<const float4*>(fcW + (size_t)vc * 128);
    const float fb = fcb[vc];
    float acc[16];
#pragma unroll
    for (int bb = 0; bb < 16; ++bb) acc[bb] = fb;
    float4 w0 = W[0], w1 = W[1];
    for (int k4 = 0; k4 < 32; ++k4) {
        float4 wn = (k4 + 2 < 32) ? W[k4 + 2] : w1;   // depth-2 prefetch
#pragma unroll
        for (int bb = 0; bb < 16; ++bb) {
            float4 a = *reinterpret_cast<const float4*>(&ol[b0 + bb][k4 * 4]);  // uniform broadcast
            acc[bb] += w0.x * a.x + w0.y * a.y + w0.z * a.z + w0.w * a.w;
        }
        w0 = w1; w1 = wn;
    }
    if (v < V) {
#pragma unroll
        for (int bb = 0; bb < 16; ++bb)
            logits[(size_t)(b0 + bb) * V + v] = acc[bb];
    }
}

extern "C" void kernel_launch(void* const* d_in, const int* in_sizes, int n_in,
                              void* d_out, int out_size, void* d_ws, size_t ws_size,
                              hipStream_t stream)
{
    const int*   gnodes = (const int*)d_in[0];
    const int*   src    = (const int*)d_in[1];
    const int*   dst    = (const int*)d_in[2];
    const float* emb    = (const float*)d_in[3];
    const float* gW     = (const float*)d_in[4];
    const float* gb     = (const float*)d_in[5];
    const float* Wih0   = (const float*)d_in[6];
    const float* Whh0   = (const float*)d_in[7];
    const float* bih0   = (const float*)d_in[8];
    const float* bhh0   = (const float*)d_in[9];
    const float* Wih1   = (const float*)d_in[10];
    const float* Whh1   = (const float*)d_in[11];
    const float* bih1   = (const float*)d_in[12];
    const float* bhh1   = (const float*)d_in[13];
    const float* fcW    = (const float*)d_in[14];
    const float* fcb    = (const float*)d_in[15];
    const float* h0     = (const float*)d_in[16];  // (2, 200, 128)
    const float* c0     = (const float*)d_in[17];

    char* ws = (char*)d_ws;
    int*   deg_out = (int*)(ws + 0);          // 12800 ints
    int*   degr    = (int*)(ws + 51200);      // 64 ints
    int*   ecount  = (int*)(ws + 51456);      // 1 int
    int*   flagA   = (int*)(ws + 51520);      // pipeline flags (own cache lines)
    int*   flagB   = (int*)(ws + 51648);
    float* agg64   = (float*)(ws + 51712);    // 64*128 -> zero region ends at 84480
    int2*  elist   = (int2*)(ws + 84480);     // CAP entries (64 KB) -> 150016
    float* h64     = (float*)(ws + 150016);   // 32 KB -> 182784
    float* Gpre0   = (float*)(ws + 182784);   // 128 KB -> 313856
    float* h0glob  = (float*)(ws + 313856);   // 32 KB -> 346624
    float* gpre1   = (float*)(ws + 346624);   // 128 KB -> 477696
    float* out64   = (float*)(ws + 477696);   // 32 KB -> 510464
    float* logits  = (float*)d_out;

    hipMemsetAsync(ws, 0, 84480, stream);     // deg_out, degr, ecount, flags, agg64

    k_deg_filter<<<E / 256, 256, 0, stream>>>(src, dst, deg_out, degr, ecount, elist);
    k_agg<<<CAP / 2, 256, 0, stream>>>(elist, ecount, gnodes, emb, deg_out, agg64);
    k_h64<<<1, 512, 0, stream>>>(agg64, degr, gW, gb, h64);
    k_gemmG<<<8, 256, 0, stream>>>(h64, Wih0, bih0, bhh0, Gpre0);

    k_lstm_pipe<<<3, 512, 0, stream>>>(Whh0, Wih1, Whh1, Gpre0, bih1, bhh1,
                                       h0 + 199 * 128, c0 + 199 * 128,
                                       h0 + (200 + 199) * 128, c0 + (200 + 199) * 128,
                                       h0glob, gpre1, out64, flagA, flagB);

    k_fc<<<(V + 63) / 64, 256, 0, stream>>>(out64, fcW, fcb, logits);
}